// Round 8
// baseline (213.402 us; speedup 1.0000x reference)
//
#include <hip/hip_runtime.h>
#include <math.h>

#define NFRAME 96
#define NTOK   197
#define NSPAT  196
#define DIM    512
#define DH     256
#define NSAMP  256
#define KSEL   49
#define SIG    0.05f
#define MPAD   208                 // padded rows per frame
#define MTOT   (NFRAME * MPAD)     // 19968 = 156*128

typedef unsigned short u16;
typedef __attribute__((ext_vector_type(8))) short bf16x8;   // 8 bf16 (4 VGPRs)
typedef __attribute__((ext_vector_type(4))) float f32x4;

__device__ __forceinline__ float gelu_exact(float v) {
    return 0.5f * v * (1.0f + erff(v * 0.70710678118654752440f));
}
__device__ __forceinline__ unsigned bf16_rne(float f) {
    unsigned u = __float_as_uint(f);
    return (u + 0x7fffu + ((u >> 16) & 1u)) >> 16;
}
__device__ __forceinline__ float bf16_to_f(unsigned h) {
    return __uint_as_float(h << 16);
}

// async global->LDS, 16B per lane. LDS dest is wave-uniform base + lane*16
// (linear); swizzling is done via the per-lane GLOBAL source address plus the
// matching XOR on the ds_read side (both-sides-or-neither rule).
__device__ __forceinline__ void gld16(const u16* g, u16* l) {
    __builtin_amdgcn_global_load_lds(
        (const __attribute__((address_space(1))) void*)g,
        (__attribute__((address_space(3))) void*)l, 16, 0, 0);
}
// swizzled 16B fragment read from a [rows][64] u16 tile (128B rows):
// chunk index cw in [0,8), stored at chunk cw ^ (row&7).
__device__ __forceinline__ bf16x8 srd(const u16* base, int r, int cw) {
    return *(const bf16x8*)((const char*)base + r * 128 + (((cw) ^ (r & 7)) << 4));
}

// ---------------------------------------------------------------------------
// K0: fused prep. blocks [0,512): weight transpose+split. blocks [512,...):
// LN + hi/lo split of x (one wave per padded row).
// ---------------------------------------------------------------------------
__global__ __launch_bounds__(256) void k0_prep(
    const float* __restrict__ x, const float* __restrict__ gamma,
    const float* __restrict__ beta,
    const float* __restrict__ w_in, const float* __restrict__ w1,
    u16* __restrict__ wiT_hi, u16* __restrict__ wiT_lo,
    u16* __restrict__ w1T_hi, u16* __restrict__ w1T_lo,
    u16* __restrict__ xs_hi, u16* __restrict__ xs_lo)
{
    if (blockIdx.x < 512) {
        const int n = blockIdx.x & 255, which = blockIdx.x >> 8;
        const float* w = which ? w1 : w_in;
        u16* th = which ? w1T_hi : wiT_hi;
        u16* tl = which ? w1T_lo : wiT_lo;
        for (int k = threadIdx.x; k < DIM; k += 256) {
            float v = w[(size_t)k * DH + n];
            unsigned hi = bf16_rne(v);
            unsigned lo = bf16_rne(v - bf16_to_f(hi));
            th[(size_t)n * DIM + k] = (u16)hi;
            tl[(size_t)n * DIM + k] = (u16)lo;
        }
        return;
    }
    const int row  = (blockIdx.x - 512) * 4 + (threadIdx.x >> 6);
    const int lane = threadIdx.x & 63;
    const int f = row / MPAD;
    int rr = row - f * MPAD; if (rr > NTOK - 1) rr = NTOK - 1;
    const float* xr = x + ((size_t)f * NTOK + rr) * DIM + lane * 8;
    float4 a = *(const float4*)xr, b4 = *(const float4*)(xr + 4);
    float e[8] = {a.x, a.y, a.z, a.w, b4.x, b4.y, b4.z, b4.w};
    float s = 0.f, sq = 0.f;
    #pragma unroll
    for (int j = 0; j < 8; ++j) { s += e[j]; sq += e[j] * e[j]; }
    #pragma unroll
    for (int o = 32; o > 0; o >>= 1) {
        s  += __shfl_xor(s,  o, 64);
        sq += __shfl_xor(sq, o, 64);
    }
    const float mu  = s * (1.f / 512.f);
    const float var = sq * (1.f / 512.f) - mu * mu;
    const float rs  = 1.f / sqrtf(var + 1e-5f);

    const float* gp = gamma + lane * 8;
    const float* bp = beta + lane * 8;
    float4 g0 = *(const float4*)gp, g1 = *(const float4*)(gp + 4);
    float4 b0 = *(const float4*)bp, b1 = *(const float4*)(bp + 4);
    float gg[8] = {g0.x, g0.y, g0.z, g0.w, g1.x, g1.y, g1.z, g1.w};
    float bt[8] = {b0.x, b0.y, b0.z, b0.w, b1.x, b1.y, b1.z, b1.w};

    unsigned hw[4], lw[4];
    #pragma unroll
    for (int p = 0; p < 4; ++p) {
        float s0 = rs * gg[2*p],   s1 = rs * gg[2*p+1];
        float v0 = e[2*p]   * s0 + (bt[2*p]   - mu * s0);
        float v1 = e[2*p+1] * s1 + (bt[2*p+1] - mu * s1);
        unsigned h0 = bf16_rne(v0), h1 = bf16_rne(v1);
        float l0 = v0 - bf16_to_f(h0), l1 = v1 - bf16_to_f(h1);
        hw[p] = h0 | (h1 << 16);
        lw[p] = bf16_rne(l0) | (bf16_rne(l1) << 16);
    }
    size_t off = (size_t)row * DIM + lane * 8;
    *(uint4*)(xs_hi + off) = make_uint4(hw[0], hw[1], hw[2], hw[3]);
    *(uint4*)(xs_lo + off) = make_uint4(lw[0], lw[1], lw[2], lw[3]);
}

// ---------------------------------------------------------------------------
// K1a: h = gelu(xs @ w_in), 3-term bf16-split MFMA.
// m97-style structure: tile 128x64, BK=64, global_load_lds width-16
// staging, single LDS buffer, 2 barriers per K-step, XOR-swizzled reads.
// LDS 48 KB -> 3 blocks/CU. Grid 624, XCD-swizzled.
// ---------------------------------------------------------------------------
__global__ __launch_bounds__(256, 3) void k1_gemm1(
    const u16* __restrict__ xs_hi, const u16* __restrict__ xs_lo,
    const u16* __restrict__ wiT_hi, const u16* __restrict__ wiT_lo,
    u16* __restrict__ h_hi, u16* __restrict__ h_lo)
{
    __shared__ u16 Ah[128][64], Al[128][64], Bh[64][64], Bl[64][64];  // 48 KB
    const int t = threadIdx.x, lane = t & 63, wv = t >> 6;
    const int linear = (blockIdx.x & 7) * 78 + (blockIdx.x >> 3);
    const int Mb = linear >> 2, Nb = linear & 3;
    const int R0 = Mb * 128, N0 = Nb * 64;
    const int wm = wv >> 1, wn = wv & 1;           // 64x32 sub-tile per wave
    const int m15 = lane & 15, q = lane >> 4;
    const int r8 = lane >> 3;                      // row within 8-row group
    const int cg = (lane & 7) ^ r8;                // pre-swizzled global chunk

    f32x4 acc[4][2];
    #pragma unroll
    for (int i = 0; i < 4; ++i)
        #pragma unroll
        for (int j = 0; j < 2; ++j)
            acc[i][j] = (f32x4){0.f, 0.f, 0.f, 0.f};

    for (int k0 = 0; k0 < DIM; k0 += 64) {
        __syncthreads();                           // prev compute done
        #pragma unroll
        for (int j = 0; j < 4; ++j) {              // A: wave stages 32 rows
            const int rA = wv * 32 + j * 8;
            const size_t src = (size_t)(R0 + rA + r8) * DIM + k0 + cg * 8;
            gld16(xs_hi + src, &Ah[rA][0]);
            gld16(xs_lo + src, &Al[rA][0]);
        }
        #pragma unroll
        for (int j = 0; j < 2; ++j) {              // B: wave stages 16 rows
            const int rB = wv * 16 + j * 8;
            const size_t src = (size_t)(N0 + rB + r8) * DIM + k0 + cg * 8;
            gld16(wiT_hi + src, &Bh[rB][0]);
            gld16(wiT_lo + src, &Bl[rB][0]);
        }
        __syncthreads();                           // vmcnt(0) drain by compiler

        #pragma unroll
        for (int kh = 0; kh < 2; ++kh) {
            const int cw = kh * 4 + q;
            bf16x8 a_h[4], a_l[4], b_h[2], b_l[2];
            #pragma unroll
            for (int i = 0; i < 4; ++i) {
                const int r = wm * 64 + i * 16 + m15;
                a_h[i] = srd(&Ah[0][0], r, cw);
                a_l[i] = srd(&Al[0][0], r, cw);
            }
            #pragma unroll
            for (int n = 0; n < 2; ++n) {
                const int r = wn * 32 + n * 16 + m15;
                b_h[n] = srd(&Bh[0][0], r, cw);
                b_l[n] = srd(&Bl[0][0], r, cw);
            }
            #pragma unroll
            for (int mt = 0; mt < 4; ++mt)
                #pragma unroll
                for (int nt = 0; nt < 2; ++nt) {
                    f32x4 c = acc[mt][nt];
                    c = __builtin_amdgcn_mfma_f32_16x16x32_bf16(a_h[mt], b_h[nt], c, 0, 0, 0);
                    c = __builtin_amdgcn_mfma_f32_16x16x32_bf16(a_l[mt], b_h[nt], c, 0, 0, 0);
                    c = __builtin_amdgcn_mfma_f32_16x16x32_bf16(a_h[mt], b_l[nt], c, 0, 0, 0);
                    acc[mt][nt] = c;
                }
        }
    }

    #pragma unroll
    for (int mt = 0; mt < 4; ++mt)
        #pragma unroll
        for (int nt = 0; nt < 2; ++nt)
            #pragma unroll
            for (int reg = 0; reg < 4; ++reg) {
                int r = R0 + wm*64 + mt*16 + q*4 + reg;
                int c = N0 + wn*32 + nt*16 + m15;
                float v = gelu_exact(acc[mt][nt][reg]);
                unsigned hb = bf16_rne(v);
                unsigned lb = bf16_rne(v - bf16_to_f(hb));
                size_t off = (size_t)r * DH + c;
                h_hi[off] = (u16)hb;
                h_lo[off] = (u16)lb;
            }
}

// ---------------------------------------------------------------------------
// K1g: per-frame g-bias: gbias[f][n] = sum_k h[f*MPAD][k] * w1b[k][n],
// k over [256,512) of w1 (the g half of the concat). Exact fp32 product of
// (hi+lo)x(hi+lo). Separate kernel (96 blocks, runs once, overlapped) --
// fusing this into k1_gemm2's prologue was measured BAD (r6: 624 blocks
// each serializing these uncoalesced reads before a 4-step K-loop ->
// k1_gemm2 45.7us @ 6% MfmaUtil).
// ---------------------------------------------------------------------------
__global__ __launch_bounds__(256) void k1g_gbias(
    const u16* __restrict__ h_hi, const u16* __restrict__ h_lo,
    const u16* __restrict__ w1T_hi, const u16* __restrict__ w1T_lo,
    float* __restrict__ gbias)
{
    const int f = blockIdx.x, n = threadIdx.x;
    const size_t hoff = (size_t)f * MPAD * DH;      // frame row-0 of h
    const size_t woff = (size_t)n * DIM + DH;       // w1T[n][256..511]
    float s = 0.f;
    for (int k = 0; k < DH; k += 8) {
        uint4 vh = *(const uint4*)(h_hi + hoff + k);
        uint4 vl = *(const uint4*)(h_lo + hoff + k);
        uint4 uh = *(const uint4*)(w1T_hi + woff + k);
        uint4 ul = *(const uint4*)(w1T_lo + woff + k);
        const unsigned* ph = (const unsigned*)&vh;
        const unsigned* pl = (const unsigned*)&vl;
        const unsigned* qh = (const unsigned*)&uh;
        const unsigned* ql = (const unsigned*)&ul;
        #pragma unroll
        for (int w = 0; w < 4; ++w) {
            float a0 = bf16_to_f(ph[w] & 0xffffu) + bf16_to_f(pl[w] & 0xffffu);
            float a1 = bf16_to_f(ph[w] >> 16)     + bf16_to_f(pl[w] >> 16);
            float b0 = bf16_to_f(qh[w] & 0xffffu) + bf16_to_f(ql[w] & 0xffffu);
            float b1 = bf16_to_f(qh[w] >> 16)     + bf16_to_f(ql[w] >> 16);
            s += a0 * b0 + a1 * b1;
        }
    }
    gbias[f * DH + n] = s;
}

// ---------------------------------------------------------------------------
// K1b: s2 = h @ w1a + gbias (per-frame), quarter-N score epilogue.
// Same m97-style structure as K1a; K = DH = 256 (4 K-steps).
// ---------------------------------------------------------------------------
__global__ __launch_bounds__(256, 3) void k1_gemm2(
    const u16* __restrict__ h_hi, const u16* __restrict__ h_lo,
    const u16* __restrict__ w1T_hi, const u16* __restrict__ w1T_lo,
    const float* __restrict__ w2, const float* __restrict__ gbias,
    float* __restrict__ s_quar)
{
    __shared__ u16 Ah[128][64], Al[128][64], Bh[64][64], Bl[64][64];  // 48 KB
    __shared__ float red[2][2][64];                                   // 1 KB
    const int t = threadIdx.x, lane = t & 63, wv = t >> 6;
    const int linear = (blockIdx.x & 7) * 78 + (blockIdx.x >> 3);
    const int Mb = linear >> 2, Nb = linear & 3;
    const int R0 = Mb * 128, N0 = Nb * 64;
    const int wm = wv >> 1, wn = wv & 1;
    const int m15 = lane & 15, q = lane >> 4;
    const int r8 = lane >> 3;
    const int cg = (lane & 7) ^ r8;

    f32x4 acc[4][2];
    #pragma unroll
    for (int i = 0; i < 4; ++i)
        #pragma unroll
        for (int j = 0; j < 2; ++j)
            acc[i][j] = (f32x4){0.f, 0.f, 0.f, 0.f};

    for (int k0 = 0; k0 < DH; k0 += 64) {
        __syncthreads();
        #pragma unroll
        for (int j = 0; j < 4; ++j) {              // A = h rows, stride DH
            const int rA = wv * 32 + j * 8;
            const size_t src = (size_t)(R0 + rA + r8) * DH + k0 + cg * 8;
            gld16(h_hi + src, &Ah[rA][0]);
            gld16(h_lo + src, &Al[rA][0]);
        }
        #pragma unroll
        for (int j = 0; j < 2; ++j) {              // B = w1T rows, k in [0,256)
            const int rB = wv * 16 + j * 8;
            const size_t src = (size_t)(N0 + rB + r8) * DIM + k0 + cg * 8;
            gld16(w1T_hi + src, &Bh[rB][0]);
            gld16(w1T_lo + src, &Bl[rB][0]);
        }
        __syncthreads();

        #pragma unroll
        for (int kh = 0; kh < 2; ++kh) {
            const int cw = kh * 4 + q;
            bf16x8 a_h[4], a_l[4], b_h[2], b_l[2];
            #pragma unroll
            for (int i = 0; i < 4; ++i) {
                const int r = wm * 64 + i * 16 + m15;
                a_h[i] = srd(&Ah[0][0], r, cw);
                a_l[i] = srd(&Al[0][0], r, cw);
            }
            #pragma unroll
            for (int n = 0; n < 2; ++n) {
                const int r = wn * 32 + n * 16 + m15;
                b_h[n] = srd(&Bh[0][0], r, cw);
                b_l[n] = srd(&Bl[0][0], r, cw);
            }
            #pragma unroll
            for (int mt = 0; mt < 4; ++mt)
                #pragma unroll
                for (int nt = 0; nt < 2; ++nt) {
                    f32x4 c = acc[mt][nt];
                    c = __builtin_amdgcn_mfma_f32_16x16x32_bf16(a_h[mt], b_h[nt], c, 0, 0, 0);
                    c = __builtin_amdgcn_mfma_f32_16x16x32_bf16(a_l[mt], b_h[nt], c, 0, 0, 0);
                    c = __builtin_amdgcn_mfma_f32_16x16x32_bf16(a_h[mt], b_l[nt], c, 0, 0, 0);
                    acc[mt][nt] = c;
                }
        }
    }

    // quarter-N epilogue: (acc + gbias) -> gelu -> .w2 -> reduce 64 cols
    float w2v[2];
    int   cIdx[2];
    #pragma unroll
    for (int nt = 0; nt < 2; ++nt) {
        cIdx[nt] = N0 + wn*32 + nt*16 + m15;
        w2v[nt]  = w2[cIdx[nt]];
    }
    #pragma unroll
    for (int mt = 0; mt < 4; ++mt)
        #pragma unroll
        for (int reg = 0; reg < 4; ++reg) {
            int r = R0 + wm*64 + mt*16 + q*4 + reg;
            int f = r / MPAD;
            float gb0 = gbias[f * DH + cIdx[0]];
            float gb1 = gbias[f * DH + cIdx[1]];
            float s = gelu_exact(acc[mt][0][reg] + gb0) * w2v[0] +
                      gelu_exact(acc[mt][1][reg] + gb1) * w2v[1];
            #pragma unroll
            for (int o = 1; o <= 8; o <<= 1)
                s += __shfl_xor(s, o, 64);
            if (m15 == 0)
                red[wn][wm][mt*16 + q*4 + reg] = s;
        }
    __syncthreads();
    if (t < 128) {
        int wmj = t >> 6, rl = t & 63;
        float sv = red[0][wmj][rl] + red[1][wmj][rl];
        s_quar[(size_t)Nb * MTOT + R0 + t] = sv;
    }
}

// ---------------------------------------------------------------------------
// K2: top-49 radix descent, LDS histogram; score = tanh(s0+s1+s2+s3).
// grid = 192, block = 1024 (16 waves, 8 samples/wave).
// NEW: TWO samples' descents interleaved per loop (independent serial
// ballot->popc->compare chains co-issue -> ~2x ILP on the latency-bound
// descent). Per-sample math bit-identical to r7; hist atomics commutative
// -> absmax canary must hold at 0.02246094.
// ---------------------------------------------------------------------------
__global__ __launch_bounds__(1024) void k2_select(
    const float* __restrict__ s_quar, const float* __restrict__ noise,
    int* __restrict__ hist2)
{
    const int fb   = blockIdx.x;
    const int f    = fb >> 1;
    const int half = fb & 1;
    const int t    = threadIdx.x;
    const int lane = t & 63;
    const int wv   = t >> 6;

    __shared__ int hist_s[KSEL * NSPAT];  // 38.4 KB
    for (int i = t; i < KSEL * NSPAT; i += 1024) hist_s[i] = 0;

    const float* s0 = s_quar;
    const float* s1 = s_quar + MTOT;
    const float* s2 = s_quar + 2 * (size_t)MTOT;
    const float* s3 = s_quar + 3 * (size_t)MTOT;
    float spv[4];
    #pragma unroll
    for (int j = 0; j < 4; ++j) {
        int l = lane + 64 * j;
        if (l < NSPAT) {
            size_t idx = (size_t)f * MPAD + 1 + l;
            spv[j] = tanhf(s0[idx] + s1[idx] + s2[idx] + s3[idx]);
        } else spv[j] = 0.f;
    }
    __syncthreads();

    const unsigned long long lmask = (1ull << lane) - 1ull;

    for (int p = 0; p < 4; ++p) {
        const int sA = half * 128 + wv * 8 + 2 * p;
        const float* nzA = noise + ((size_t)f * NSAMP + sA) * NSPAT;
        const float* nzB = nzA + NSPAT;
        unsigned keyA[4], keyB[4];
        #pragma unroll
        for (int j = 0; j < 4; ++j) {
            int l = lane + 64 * j;
            if (l < NSPAT) {
                float pa = spv[j] + nzA[l] * SIG;
                float pb = spv[j] + nzB[l] * SIG;
                unsigned ua = __float_as_uint(pa);
                unsigned ub = __float_as_uint(pb);
                keyA[j] = (ua & 0x80000000u) ? ~ua : (ua | 0x80000000u);
                keyB[j] = (ub & 0x80000000u) ? ~ub : (ub | 0x80000000u);
            } else {
                keyA[j] = 0u;
                keyB[j] = 0u;
            }
        }

        // seed both descents: bit31 ballot decides bits 31..30
        unsigned ansA, ansB;
        bool doneA, doneB;
        {
            int cA = 0, cB = 0;
            #pragma unroll
            for (int j = 0; j < 4; ++j) {
                cA += __popcll(__ballot(keyA[j] >= 0x80000000u));
                cB += __popcll(__ballot(keyB[j] >= 0x80000000u));
            }
            ansA = (cA >= KSEL) ? 0x80000000u : 0x40000000u;
            ansB = (cB >= KSEL) ? 0x80000000u : 0x40000000u;
            doneA = (cA == KSEL);
            doneB = (cB == KSEL);
        }
        for (int bit = 29; bit >= 0; --bit) {
            if (doneA && doneB) break;            // wave-uniform
            unsigned candA = ansA | (1u << bit);
            unsigned candB = ansB | (1u << bit);
            int cntA = 0, cntB = 0;
            #pragma unroll
            for (int j = 0; j < 4; ++j) {
                cntA += __popcll(__ballot(keyA[j] >= candA));
                cntB += __popcll(__ballot(keyB[j] >= candB));
            }
            if (!doneA && cntA >= KSEL) {
                ansA = candA;
                if (cntA == KSEL) doneA = true;   // exact: {>=ans} is top-49
            }
            if (!doneB && cntB >= KSEL) {
                ansB = candB;
                if (cntB == KSEL) doneB = true;
            }
        }

        // selection + histogram for both samples (sequential, independent)
        #pragma unroll
        for (int which = 0; which < 2; ++which) {
            const unsigned* key = which ? keyB : keyA;
            const unsigned  ans = which ? ansB : ansA;
            unsigned long long eq[4];
            int cgt = 0;
            #pragma unroll
            for (int j = 0; j < 4; ++j) {
                cgt += __popcll(__ballot(key[j] > ans));
                eq[j] = __ballot(key[j] == ans);
            }
            const int quota = KSEL - cgt;
            int eqpre[4]; { int run = 0;
                #pragma unroll
                for (int j = 0; j < 4; ++j) { eqpre[j] = run; run += __popcll(eq[j]); } }

            int pre = 0;
            #pragma unroll
            for (int j = 0; j < 4; ++j) {
                bool iseq = (key[j] == ans);
                int trk = eqpre[j] + __popcll(eq[j] & lmask);
                bool selj = (key[j] > ans) || (iseq && trk < quota);
                unsigned long long sb = __ballot(selj);
                int rk = pre + __popcll(sb & lmask);
                if (selj)
                    atomicAdd(&hist_s[rk * NSPAT + lane + 64 * j], 1);
                pre += __popcll(sb);
            }
        }
    }

    __syncthreads();
    int* hb = hist2 + (size_t)fb * (KSEL * NSPAT);
    for (int i = t; i < KSEL * NSPAT; i += 1024)
        hb[i] = hist_s[i];
}

// ---------------------------------------------------------------------------
// K3: out = [cls | (hist/256) @ spat]. Disjoint d x8 split (no atomics):
// grid = 96 x 8 = 768 blocks, 64 cols/block, full 196-l loop with 7
// independent loads in flight. LDS hist [l][k] padded to 52; inner-loop
// weight read is one ds_read_b128.
// ---------------------------------------------------------------------------
#define KP3 52
__global__ __launch_bounds__(256) void k3_output(
    const float* __restrict__ x, const int* __restrict__ hist2,
    float* __restrict__ out)
{
    const int b   = blockIdx.x >> 3;
    const int ds  = blockIdx.x & 7;
    const int d0  = ds * 64;
    const int t   = threadIdx.x;
    const int tdc = t & 15;           // 16 float4 column groups (64 cols)
    const int tk  = t >> 4;           // 16 k-groups; k = tk*4 + i

    __shared__ float hist_s[NSPAT * KP3 + 16];   // 40.9 KB, [l][k] (+ghost tail)

    const int* h0 = hist2 + (size_t)(2 * b) * (KSEL * NSPAT);
    const int* h1 = h0 + KSEL * NSPAT;
    for (int i = t; i < KSEL * NSPAT; i += 256) {
        int k = i / NSPAT;
        int l = i - k * NSPAT;
        hist_s[l * KP3 + k] = (float)(h0[i] + h1[i]);
    }
    for (int i = t; i < NSPAT * 3 + 16; i += 256) {   // ghost k = 49..51 + tail
        int l = i / 3, j = i - l * 3;
        int idx = (i < NSPAT * 3) ? (l * KP3 + KSEL + j) : (NSPAT * KP3 + i - NSPAT * 3);
        hist_s[idx] = 0.f;
    }
    if (t < 64)
        out[(size_t)b * 50 * DIM + d0 + t] = x[(size_t)b * NTOK * DIM + d0 + t];
    __syncthreads();

    const float* xs = x + ((size_t)b * NTOK + 1) * DIM + d0 + tdc * 4;
    float4 acc[4];
    #pragma unroll
    for (int i = 0; i < 4; ++i) acc[i] = make_float4(0.f, 0.f, 0.f, 0.f);

    #pragma unroll 7
    for (int l = 0; l < NSPAT; ++l) {
        float4 v  = *(const float4*)(xs + (size_t)l * DIM);
        float4 w4 = *(const float4*)&hist_s[l * KP3 + tk * 4];   // 1x ds_read_b128
        acc[0].x += w4.x * v.x; acc[0].y += w4.x * v.y;
        acc[0].z += w4.x * v.z; acc[0].w += w4.x * v.w;
        acc[1].x += w4.y * v.x; acc[1].y += w4.y * v.y;
        acc[1].z += w4.y * v.z; acc[1].w += w4.y * v.w;
        acc[2].x += w4.z * v.x; acc[2].y += w4.z * v.y;
        acc[2].z += w4.z * v.z; acc[2].w += w4.z * v.w;
        acc[3].x += w4.w * v.x; acc[3].y += w4.w * v.y;
        acc[3].z += w4.w * v.z; acc[3].w += w4.w * v.w;
    }

    const float inv = 1.f / 256.f;
    #pragma unroll
    for (int i = 0; i < 4; ++i) {
        int k = tk * 4 + i;
        if (k < KSEL) {
            float4 o = make_float4(acc[i].x * inv, acc[i].y * inv,
                                   acc[i].z * inv, acc[i].w * inv);
            *(float4*)&out[((size_t)b * 50 + 1 + k) * DIM + d0 + tdc * 4] = o;
        }
    }
}

// ---------------------------------------------------------------------------
extern "C" void kernel_launch(void* const* d_in, const int* in_sizes, int n_in,
                              void* d_out, int out_size, void* d_ws, size_t ws_size,
                              hipStream_t stream)
{
    const float* x     = (const float*)d_in[0];
    const float* noise = (const float*)d_in[1];
    const float* gamma = (const float*)d_in[2];
    const float* beta  = (const float*)d_in[3];
    const float* w_in  = (const float*)d_in[4];
    const float* w1    = (const float*)d_in[5];
    const float* w2    = (const float*)d_in[6];
    float* out = (float*)d_out;

    // ws layout (bytes; total ~70.1 MB)
    char* ws = (char*)d_ws;
    int*   hist2   = (int*)  (ws + 0);            // 192*49*196*4 = 7,375,872
    float* gbias   = (float*)(ws + 0);            // 96*256*4 = 98,304 — aliases
                                                  // hist2: K1g writes, K1b reads,
                                                  // then K2 fully overwrites.
    float* s_quar  = (float*)(ws + 7375872);      // 4*19968*4    =   319,488
    u16*   wiT_hi  = (u16*)  (ws + 7695360);      // 256*512*2    =   262,144
    u16*   wiT_lo  = (u16*)  (ws + 7957504);
    u16*   w1T_hi  = (u16*)  (ws + 8219648);
    u16*   w1T_lo  = (u16*)  (ws + 8481792);
    u16*   h_hi    = (u16*)  (ws + 8743936);      // 19968*256*2  = 10,223,616
    u16*   h_lo    = (u16*)  (ws + 18967552);
    u16*   xs_hi   = (u16*)  (ws + 29191168);     // 19968*512*2  = 20,447,232
    u16*   xs_lo   = (u16*)  (ws + 49638400);     // end 70,085,632

    k0_prep<<<512 + MTOT / 4, 256, 0, stream>>>(x, gamma, beta, w_in, w1,
                                                wiT_hi, wiT_lo, w1T_hi, w1T_lo,
                                                xs_hi, xs_lo);
    k1_gemm1<<<(MTOT / 128) * 4, 256, 0, stream>>>(xs_hi, xs_lo, wiT_hi, wiT_lo,
                                                   h_hi, h_lo);
    k1g_gbias<<<NFRAME, 256, 0, stream>>>(h_hi, h_lo, w1T_hi, w1T_lo, gbias);
    k1_gemm2<<<(MTOT / 128) * 4, 256, 0, stream>>>(h_hi, h_lo, w1T_hi, w1T_lo,
                                                   w2, gbias, s_quar);
    k2_select<<<NFRAME * 2, 1024, 0, stream>>>(s_quar, noise, hist2);
    k3_output<<<NFRAME * 8, 256, 0, stream>>>(x, hist2, out);
}

// Round 11
// 198.854 us; speedup vs baseline: 1.0732x; 1.0732x over previous
//
#include <hip/hip_runtime.h>
#include <math.h>

#define NFRAME 96
#define NTOK   197
#define NSPAT  196
#define DIM    512
#define DH     256
#define NSAMP  256
#define KSEL   49
#define SIG    0.05f
#define MPAD   208                 // padded rows per frame
#define MTOT   (NFRAME * MPAD)     // 19968 = 156*128
#define HSEG   (KSEL * NSPAT)      // 9604 histogram elements per segment

typedef unsigned short u16;
typedef __attribute__((ext_vector_type(8))) short bf16x8;   // 8 bf16 (4 VGPRs)
typedef __attribute__((ext_vector_type(4))) float f32x4;

__device__ __forceinline__ float gelu_exact(float v) {
    return 0.5f * v * (1.0f + erff(v * 0.70710678118654752440f));
}
__device__ __forceinline__ unsigned bf16_rne(float f) {
    unsigned u = __float_as_uint(f);
    return (u + 0x7fffu + ((u >> 16) & 1u)) >> 16;
}
__device__ __forceinline__ float bf16_to_f(unsigned h) {
    return __uint_as_float(h << 16);
}

// async global->LDS, 16B per lane. LDS dest is wave-uniform base + lane*16
// (linear); swizzling is done via the per-lane GLOBAL source address plus the
// matching XOR on the ds_read side (both-sides-or-neither rule).
__device__ __forceinline__ void gld16(const u16* g, u16* l) {
    __builtin_amdgcn_global_load_lds(
        (const __attribute__((address_space(1))) void*)g,
        (__attribute__((address_space(3))) void*)l, 16, 0, 0);
}
// swizzled 16B fragment read from a [rows][64] u16 tile (128B rows):
// chunk index cw in [0,8), stored at chunk cw ^ (row&7).
__device__ __forceinline__ bf16x8 srd(const u16* base, int r, int cw) {
    return *(const bf16x8*)((const char*)base + r * 128 + (((cw) ^ (r & 7)) << 4));
}

// ---------------------------------------------------------------------------
// K0: fused prep. blocks [0,512): weight transpose+split. blocks [512,...):
// LN + hi/lo split of x (one wave per padded row).
// ---------------------------------------------------------------------------
__global__ __launch_bounds__(256) void k0_prep(
    const float* __restrict__ x, const float* __restrict__ gamma,
    const float* __restrict__ beta,
    const float* __restrict__ w_in, const float* __restrict__ w1,
    u16* __restrict__ wiT_hi, u16* __restrict__ wiT_lo,
    u16* __restrict__ w1T_hi, u16* __restrict__ w1T_lo,
    u16* __restrict__ xs_hi, u16* __restrict__ xs_lo)
{
    if (blockIdx.x < 512) {
        const int n = blockIdx.x & 255, which = blockIdx.x >> 8;
        const float* w = which ? w1 : w_in;
        u16* th = which ? w1T_hi : wiT_hi;
        u16* tl = which ? w1T_lo : wiT_lo;
        for (int k = threadIdx.x; k < DIM; k += 256) {
            float v = w[(size_t)k * DH + n];
            unsigned hi = bf16_rne(v);
            unsigned lo = bf16_rne(v - bf16_to_f(hi));
            th[(size_t)n * DIM + k] = (u16)hi;
            tl[(size_t)n * DIM + k] = (u16)lo;
        }
        return;
    }
    const int row  = (blockIdx.x - 512) * 4 + (threadIdx.x >> 6);
    const int lane = threadIdx.x & 63;
    const int f = row / MPAD;
    int rr = row - f * MPAD; if (rr > NTOK - 1) rr = NTOK - 1;
    const float* xr = x + ((size_t)f * NTOK + rr) * DIM + lane * 8;
    float4 a = *(const float4*)xr, b4 = *(const float4*)(xr + 4);
    float e[8] = {a.x, a.y, a.z, a.w, b4.x, b4.y, b4.z, b4.w};
    float s = 0.f, sq = 0.f;
    #pragma unroll
    for (int j = 0; j < 8; ++j) { s += e[j]; sq += e[j] * e[j]; }
    #pragma unroll
    for (int o = 32; o > 0; o >>= 1) {
        s  += __shfl_xor(s,  o, 64);
        sq += __shfl_xor(sq, o, 64);
    }
    const float mu  = s * (1.f / 512.f);
    const float var = sq * (1.f / 512.f) - mu * mu;
    const float rs  = 1.f / sqrtf(var + 1e-5f);

    const float* gp = gamma + lane * 8;
    const float* bp = beta + lane * 8;
    float4 g0 = *(const float4*)gp, g1 = *(const float4*)(gp + 4);
    float4 b0 = *(const float4*)bp, b1 = *(const float4*)(bp + 4);
    float gg[8] = {g0.x, g0.y, g0.z, g0.w, g1.x, g1.y, g1.z, g1.w};
    float bt[8] = {b0.x, b0.y, b0.z, b0.w, b1.x, b1.y, b1.z, b1.w};

    unsigned hw[4], lw[4];
    #pragma unroll
    for (int p = 0; p < 4; ++p) {
        float s0 = rs * gg[2*p],   s1 = rs * gg[2*p+1];
        float v0 = e[2*p]   * s0 + (bt[2*p]   - mu * s0);
        float v1 = e[2*p+1] * s1 + (bt[2*p+1] - mu * s1);
        unsigned h0 = bf16_rne(v0), h1 = bf16_rne(v1);
        float l0 = v0 - bf16_to_f(h0), l1 = v1 - bf16_to_f(h1);
        hw[p] = h0 | (h1 << 16);
        lw[p] = bf16_rne(l0) | (bf16_rne(l1) << 16);
    }
    size_t off = (size_t)row * DIM + lane * 8;
    *(uint4*)(xs_hi + off) = make_uint4(hw[0], hw[1], hw[2], hw[3]);
    *(uint4*)(xs_lo + off) = make_uint4(lw[0], lw[1], lw[2], lw[3]);
}

// ---------------------------------------------------------------------------
// K1a: h = gelu(xs @ w_in), 3-term bf16-split MFMA.
// m97-style structure: tile 128x64, BK=64, global_load_lds width-16
// staging, single LDS buffer, 2 barriers per K-step, XOR-swizzled reads.
// LDS 48 KB -> 3 blocks/CU. Grid 624, XCD-swizzled.
// ---------------------------------------------------------------------------
__global__ __launch_bounds__(256, 3) void k1_gemm1(
    const u16* __restrict__ xs_hi, const u16* __restrict__ xs_lo,
    const u16* __restrict__ wiT_hi, const u16* __restrict__ wiT_lo,
    u16* __restrict__ h_hi, u16* __restrict__ h_lo)
{
    __shared__ u16 Ah[128][64], Al[128][64], Bh[64][64], Bl[64][64];  // 48 KB
    const int t = threadIdx.x, lane = t & 63, wv = t >> 6;
    const int linear = (blockIdx.x & 7) * 78 + (blockIdx.x >> 3);
    const int Mb = linear >> 2, Nb = linear & 3;
    const int R0 = Mb * 128, N0 = Nb * 64;
    const int wm = wv >> 1, wn = wv & 1;           // 64x32 sub-tile per wave
    const int m15 = lane & 15, q = lane >> 4;
    const int r8 = lane >> 3;                      // row within 8-row group
    const int cg = (lane & 7) ^ r8;                // pre-swizzled global chunk

    f32x4 acc[4][2];
    #pragma unroll
    for (int i = 0; i < 4; ++i)
        #pragma unroll
        for (int j = 0; j < 2; ++j)
            acc[i][j] = (f32x4){0.f, 0.f, 0.f, 0.f};

    for (int k0 = 0; k0 < DIM; k0 += 64) {
        __syncthreads();                           // prev compute done
        #pragma unroll
        for (int j = 0; j < 4; ++j) {              // A: wave stages 32 rows
            const int rA = wv * 32 + j * 8;
            const size_t src = (size_t)(R0 + rA + r8) * DIM + k0 + cg * 8;
            gld16(xs_hi + src, &Ah[rA][0]);
            gld16(xs_lo + src, &Al[rA][0]);
        }
        #pragma unroll
        for (int j = 0; j < 2; ++j) {              // B: wave stages 16 rows
            const int rB = wv * 16 + j * 8;
            const size_t src = (size_t)(N0 + rB + r8) * DIM + k0 + cg * 8;
            gld16(wiT_hi + src, &Bh[rB][0]);
            gld16(wiT_lo + src, &Bl[rB][0]);
        }
        __syncthreads();                           // vmcnt(0) drain by compiler

        #pragma unroll
        for (int kh = 0; kh < 2; ++kh) {
            const int cw = kh * 4 + q;
            bf16x8 a_h[4], a_l[4], b_h[2], b_l[2];
            #pragma unroll
            for (int i = 0; i < 4; ++i) {
                const int r = wm * 64 + i * 16 + m15;
                a_h[i] = srd(&Ah[0][0], r, cw);
                a_l[i] = srd(&Al[0][0], r, cw);
            }
            #pragma unroll
            for (int n = 0; n < 2; ++n) {
                const int r = wn * 32 + n * 16 + m15;
                b_h[n] = srd(&Bh[0][0], r, cw);
                b_l[n] = srd(&Bl[0][0], r, cw);
            }
            #pragma unroll
            for (int mt = 0; mt < 4; ++mt)
                #pragma unroll
                for (int nt = 0; nt < 2; ++nt) {
                    f32x4 c = acc[mt][nt];
                    c = __builtin_amdgcn_mfma_f32_16x16x32_bf16(a_h[mt], b_h[nt], c, 0, 0, 0);
                    c = __builtin_amdgcn_mfma_f32_16x16x32_bf16(a_l[mt], b_h[nt], c, 0, 0, 0);
                    c = __builtin_amdgcn_mfma_f32_16x16x32_bf16(a_h[mt], b_l[nt], c, 0, 0, 0);
                    acc[mt][nt] = c;
                }
        }
    }

    #pragma unroll
    for (int mt = 0; mt < 4; ++mt)
        #pragma unroll
        for (int nt = 0; nt < 2; ++nt)
            #pragma unroll
            for (int reg = 0; reg < 4; ++reg) {
                int r = R0 + wm*64 + mt*16 + q*4 + reg;
                int c = N0 + wn*32 + nt*16 + m15;
                float v = gelu_exact(acc[mt][nt][reg]);
                unsigned hb = bf16_rne(v);
                unsigned lb = bf16_rne(v - bf16_to_f(hb));
                size_t off = (size_t)r * DH + c;
                h_hi[off] = (u16)hb;
                h_lo[off] = (u16)lb;
            }
}

// ---------------------------------------------------------------------------
// K1g: per-frame g-bias: gbias[f][n] = sum_k h[f*MPAD][k] * w1b[k][n],
// k over [256,512) of w1 (the g half of the concat). Exact fp32 product of
// (hi+lo)x(hi+lo). Separate kernel (96 blocks, runs once, overlapped) --
// fusing this into k1_gemm2's prologue was measured BAD (r6: 624 blocks
// each serializing these uncoalesced reads before a 4-step K-loop ->
// k1_gemm2 45.7us @ 6% MfmaUtil).
// ---------------------------------------------------------------------------
__global__ __launch_bounds__(256) void k1g_gbias(
    const u16* __restrict__ h_hi, const u16* __restrict__ h_lo,
    const u16* __restrict__ w1T_hi, const u16* __restrict__ w1T_lo,
    float* __restrict__ gbias)
{
    const int f = blockIdx.x, n = threadIdx.x;
    const size_t hoff = (size_t)f * MPAD * DH;      // frame row-0 of h
    const size_t woff = (size_t)n * DIM + DH;       // w1T[n][256..511]
    float s = 0.f;
    for (int k = 0; k < DH; k += 8) {
        uint4 vh = *(const uint4*)(h_hi + hoff + k);
        uint4 vl = *(const uint4*)(h_lo + hoff + k);
        uint4 uh = *(const uint4*)(w1T_hi + woff + k);
        uint4 ul = *(const uint4*)(w1T_lo + woff + k);
        const unsigned* ph = (const unsigned*)&vh;
        const unsigned* pl = (const unsigned*)&vl;
        const unsigned* qh = (const unsigned*)&uh;
        const unsigned* ql = (const unsigned*)&ul;
        #pragma unroll
        for (int w = 0; w < 4; ++w) {
            float a0 = bf16_to_f(ph[w] & 0xffffu) + bf16_to_f(pl[w] & 0xffffu);
            float a1 = bf16_to_f(ph[w] >> 16)     + bf16_to_f(pl[w] >> 16);
            float b0 = bf16_to_f(qh[w] & 0xffffu) + bf16_to_f(ql[w] & 0xffffu);
            float b1 = bf16_to_f(qh[w] >> 16)     + bf16_to_f(ql[w] >> 16);
            s += a0 * b0 + a1 * b1;
        }
    }
    gbias[f * DH + n] = s;
}

// ---------------------------------------------------------------------------
// K1b: s2 = h @ w1a + gbias (per-frame), quarter-N score epilogue.
// Same m97-style structure as K1a; K = DH = 256 (4 K-steps).
// ---------------------------------------------------------------------------
__global__ __launch_bounds__(256, 3) void k1_gemm2(
    const u16* __restrict__ h_hi, const u16* __restrict__ h_lo,
    const u16* __restrict__ w1T_hi, const u16* __restrict__ w1T_lo,
    const float* __restrict__ w2, const float* __restrict__ gbias,
    float* __restrict__ s_quar)
{
    __shared__ u16 Ah[128][64], Al[128][64], Bh[64][64], Bl[64][64];  // 48 KB
    __shared__ float red[2][2][64];                                   // 1 KB
    const int t = threadIdx.x, lane = t & 63, wv = t >> 6;
    const int linear = (blockIdx.x & 7) * 78 + (blockIdx.x >> 3);
    const int Mb = linear >> 2, Nb = linear & 3;
    const int R0 = Mb * 128, N0 = Nb * 64;
    const int wm = wv >> 1, wn = wv & 1;
    const int m15 = lane & 15, q = lane >> 4;
    const int r8 = lane >> 3;
    const int cg = (lane & 7) ^ r8;

    f32x4 acc[4][2];
    #pragma unroll
    for (int i = 0; i < 4; ++i)
        #pragma unroll
        for (int j = 0; j < 2; ++j)
            acc[i][j] = (f32x4){0.f, 0.f, 0.f, 0.f};

    for (int k0 = 0; k0 < DH; k0 += 64) {
        __syncthreads();
        #pragma unroll
        for (int j = 0; j < 4; ++j) {              // A = h rows, stride DH
            const int rA = wv * 32 + j * 8;
            const size_t src = (size_t)(R0 + rA + r8) * DH + k0 + cg * 8;
            gld16(h_hi + src, &Ah[rA][0]);
            gld16(h_lo + src, &Al[rA][0]);
        }
        #pragma unroll
        for (int j = 0; j < 2; ++j) {              // B = w1T rows, k in [0,256)
            const int rB = wv * 16 + j * 8;
            const size_t src = (size_t)(N0 + rB + r8) * DIM + k0 + cg * 8;
            gld16(w1T_hi + src, &Bh[rB][0]);
            gld16(w1T_lo + src, &Bl[rB][0]);
        }
        __syncthreads();

        #pragma unroll
        for (int kh = 0; kh < 2; ++kh) {
            const int cw = kh * 4 + q;
            bf16x8 a_h[4], a_l[4], b_h[2], b_l[2];
            #pragma unroll
            for (int i = 0; i < 4; ++i) {
                const int r = wm * 64 + i * 16 + m15;
                a_h[i] = srd(&Ah[0][0], r, cw);
                a_l[i] = srd(&Al[0][0], r, cw);
            }
            #pragma unroll
            for (int n = 0; n < 2; ++n) {
                const int r = wn * 32 + n * 16 + m15;
                b_h[n] = srd(&Bh[0][0], r, cw);
                b_l[n] = srd(&Bl[0][0], r, cw);
            }
            #pragma unroll
            for (int mt = 0; mt < 4; ++mt)
                #pragma unroll
                for (int nt = 0; nt < 2; ++nt) {
                    f32x4 c = acc[mt][nt];
                    c = __builtin_amdgcn_mfma_f32_16x16x32_bf16(a_h[mt], b_h[nt], c, 0, 0, 0);
                    c = __builtin_amdgcn_mfma_f32_16x16x32_bf16(a_l[mt], b_h[nt], c, 0, 0, 0);
                    c = __builtin_amdgcn_mfma_f32_16x16x32_bf16(a_h[mt], b_l[nt], c, 0, 0, 0);
                    acc[mt][nt] = c;
                }
        }
    }

    // quarter-N epilogue: (acc + gbias) -> gelu -> .w2 -> reduce 64 cols
    float w2v[2];
    int   cIdx[2];
    #pragma unroll
    for (int nt = 0; nt < 2; ++nt) {
        cIdx[nt] = N0 + wn*32 + nt*16 + m15;
        w2v[nt]  = w2[cIdx[nt]];
    }
    #pragma unroll
    for (int mt = 0; mt < 4; ++mt)
        #pragma unroll
        for (int reg = 0; reg < 4; ++reg) {
            int r = R0 + wm*64 + mt*16 + q*4 + reg;
            int f = r / MPAD;
            float gb0 = gbias[f * DH + cIdx[0]];
            float gb1 = gbias[f * DH + cIdx[1]];
            float s = gelu_exact(acc[mt][0][reg] + gb0) * w2v[0] +
                      gelu_exact(acc[mt][1][reg] + gb1) * w2v[1];
            #pragma unroll
            for (int o = 1; o <= 8; o <<= 1)
                s += __shfl_xor(s, o, 64);
            if (m15 == 0)
                red[wn][wm][mt*16 + q*4 + reg] = s;
        }
    __syncthreads();
    if (t < 128) {
        int wmj = t >> 6, rl = t & 63;
        float sv = red[0][wmj][rl] + red[1][wmj][rl];
        s_quar[(size_t)Nb * MTOT + R0 + t] = sv;
    }
}

// ---------------------------------------------------------------------------
// K2: top-49 radix descent, LDS histogram; score = tanh(s0+s1+s2+s3).
// Inner loop = r7-proven single-sample descent (r8's 2-sample interleave
// regressed: TLP already hid ballot latency; reg pressure hurt).
// 4 blocks per frame (64 samples each), grid 384 -> all 256 CUs busy
// (~1.7x descent throughput vs 192 blocks on 192 CUs). Counts <= 64 fit
// u16, so 384 segments x 9604 x 2B == old 2x int layout: ws unchanged.
// ---------------------------------------------------------------------------
__global__ __launch_bounds__(1024) void k2_select(
    const float* __restrict__ s_quar, const float* __restrict__ noise,
    u16* __restrict__ hist2)
{
    const int fb   = blockIdx.x;
    const int f    = fb >> 2;
    const int qt   = fb & 3;
    const int t    = threadIdx.x;
    const int lane = t & 63;
    const int wv   = t >> 6;

    __shared__ int hist_s[HSEG];  // 38.4 KB
    for (int i = t; i < HSEG; i += 1024) hist_s[i] = 0;

    const float* s0 = s_quar;
    const float* s1 = s_quar + MTOT;
    const float* s2 = s_quar + 2 * (size_t)MTOT;
    const float* s3 = s_quar + 3 * (size_t)MTOT;
    float spv[4];
    #pragma unroll
    for (int j = 0; j < 4; ++j) {
        int l = lane + 64 * j;
        if (l < NSPAT) {
            size_t idx = (size_t)f * MPAD + 1 + l;
            spv[j] = tanhf(s0[idx] + s1[idx] + s2[idx] + s3[idx]);
        } else spv[j] = 0.f;
    }
    __syncthreads();

    const unsigned long long lmask = (1ull << lane) - 1ull;

    for (int si = 0; si < 4; ++si) {
        const int s = qt * 64 + wv * 4 + si;
        const float* nz = noise + ((size_t)f * NSAMP + s) * NSPAT;
        unsigned key[4];
        #pragma unroll
        for (int j = 0; j < 4; ++j) {
            int l = lane + 64 * j;
            if (l < NSPAT) {
                float p = spv[j] + nz[l] * SIG;
                unsigned u = __float_as_uint(p);
                key[j] = (u & 0x80000000u) ? ~u : (u | 0x80000000u);
            } else {
                key[j] = 0u;
            }
        }

        unsigned ans;
        int c31 = 0;
        {
            #pragma unroll
            for (int j = 0; j < 4; ++j)
                c31 += __popcll(__ballot(key[j] >= 0x80000000u));
            ans = (c31 >= KSEL) ? 0x80000000u : 0x40000000u;
        }
        if (c31 != KSEL) {
            for (int bit = 29; bit >= 0; --bit) {
                unsigned cand = ans | (1u << bit);
                int cnt = 0;
                #pragma unroll
                for (int j = 0; j < 4; ++j)
                    cnt += __popcll(__ballot(key[j] >= cand));
                if (cnt >= KSEL) {
                    ans = cand;
                    if (cnt == KSEL) break;     // exact: {>=ans} is the top-49
                }
            }
        }

        unsigned long long eq[4];
        int cgt = 0;
        #pragma unroll
        for (int j = 0; j < 4; ++j) {
            cgt += __popcll(__ballot(key[j] > ans));
            eq[j] = __ballot(key[j] == ans);
        }
        const int quota = KSEL - cgt;
        int eqpre[4]; { int run = 0;
            #pragma unroll
            for (int j = 0; j < 4; ++j) { eqpre[j] = run; run += __popcll(eq[j]); } }

        int pre = 0;
        #pragma unroll
        for (int j = 0; j < 4; ++j) {
            bool iseq = (key[j] == ans);
            int trk = eqpre[j] + __popcll(eq[j] & lmask);
            bool selj = (key[j] > ans) || (iseq && trk < quota);
            unsigned long long sb = __ballot(selj);
            int rk = pre + __popcll(sb & lmask);
            if (selj)
                atomicAdd(&hist_s[rk * NSPAT + lane + 64 * j], 1);
            pre += __popcll(sb);
        }
    }

    __syncthreads();
    u16* hb = hist2 + (size_t)fb * HSEG;
    for (int i = t; i < HSEG; i += 1024)
        hb[i] = (u16)hist_s[i];
}

// ---------------------------------------------------------------------------
// K3: out = [cls | (hist/256) @ spat]. Disjoint d x8 split (no atomics):
// grid = 96 x 8 = 768 blocks, 64 cols/block, full 196-l loop with 7
// independent loads in flight. LDS hist [l][k] padded to 52; inner-loop
// weight read is one ds_read_b128. Sums 4 u16 hist segments per frame
// (same bytes as the old 2 int segments).
// ---------------------------------------------------------------------------
#define KP3 52
__global__ __launch_bounds__(256) void k3_output(
    const float* __restrict__ x, const u16* __restrict__ hist2,
    float* __restrict__ out)
{
    const int b   = blockIdx.x >> 3;
    const int ds  = blockIdx.x & 7;
    const int d0  = ds * 64;
    const int t   = threadIdx.x;
    const int tdc = t & 15;           // 16 float4 column groups (64 cols)
    const int tk  = t >> 4;           // 16 k-groups; k = tk*4 + i

    __shared__ float hist_s[NSPAT * KP3 + 16];   // 40.9 KB, [l][k] (+ghost tail)

    const u16* hbase = hist2 + (size_t)(4 * b) * HSEG;
    for (int i = t; i < HSEG; i += 256) {
        int k = i / NSPAT;
        int l = i - k * NSPAT;
        int sum = (int)hbase[i] + (int)hbase[i + HSEG]
                + (int)hbase[i + 2 * HSEG] + (int)hbase[i + 3 * HSEG];
        hist_s[l * KP3 + k] = (float)sum;
    }
    for (int i = t; i < NSPAT * 3 + 16; i += 256) {   // ghost k = 49..51 + tail
        int l = i / 3, j = i - l * 3;
        int idx = (i < NSPAT * 3) ? (l * KP3 + KSEL + j) : (NSPAT * KP3 + i - NSPAT * 3);
        hist_s[idx] = 0.f;
    }
    if (t < 64)
        out[(size_t)b * 50 * DIM + d0 + t] = x[(size_t)b * NTOK * DIM + d0 + t];
    __syncthreads();

    const float* xs = x + ((size_t)b * NTOK + 1) * DIM + d0 + tdc * 4;
    float4 acc[4];
    #pragma unroll
    for (int i = 0; i < 4; ++i) acc[i] = make_float4(0.f, 0.f, 0.f, 0.f);

    #pragma unroll 7
    for (int l = 0; l < NSPAT; ++l) {
        float4 v  = *(const float4*)(xs + (size_t)l * DIM);
        float4 w4 = *(const float4*)&hist_s[l * KP3 + tk * 4];   // 1x ds_read_b128
        acc[0].x += w4.x * v.x; acc[0].y += w4.x * v.y;
        acc[0].z += w4.x * v.z; acc[0].w += w4.x * v.w;
        acc[1].x += w4.y * v.x; acc[1].y += w4.y * v.y;
        acc[1].z += w4.y * v.z; acc[1].w += w4.y * v.w;
        acc[2].x += w4.z * v.x; acc[2].y += w4.z * v.y;
        acc[2].z += w4.z * v.z; acc[2].w += w4.z * v.w;
        acc[3].x += w4.w * v.x; acc[3].y += w4.w * v.y;
        acc[3].z += w4.w * v.z; acc[3].w += w4.w * v.w;
    }

    const float inv = 1.f / 256.f;
    #pragma unroll
    for (int i = 0; i < 4; ++i) {
        int k = tk * 4 + i;
        if (k < KSEL) {
            float4 o = make_float4(acc[i].x * inv, acc[i].y * inv,
                                   acc[i].z * inv, acc[i].w * inv);
            *(float4*)&out[((size_t)b * 50 + 1 + k) * DIM + d0 + tdc * 4] = o;
        }
    }
}

// ---------------------------------------------------------------------------
extern "C" void kernel_launch(void* const* d_in, const int* in_sizes, int n_in,
                              void* d_out, int out_size, void* d_ws, size_t ws_size,
                              hipStream_t stream)
{
    const float* x     = (const float*)d_in[0];
    const float* noise = (const float*)d_in[1];
    const float* gamma = (const float*)d_in[2];
    const float* beta  = (const float*)d_in[3];
    const float* w_in  = (const float*)d_in[4];
    const float* w1    = (const float*)d_in[5];
    const float* w2    = (const float*)d_in[6];
    float* out = (float*)d_out;

    // ws layout (bytes; total ~70.1 MB — unchanged)
    char* ws = (char*)d_ws;
    u16*   hist2   = (u16*)  (ws + 0);            // 384*9604*2 = 7,375,872
    float* gbias   = (float*)(ws + 0);            // 96*256*4 = 98,304 — aliases
                                                  // hist2: K1g writes, K1b reads,
                                                  // then K2 fully overwrites.
    float* s_quar  = (float*)(ws + 7375872);      // 4*19968*4    =   319,488
    u16*   wiT_hi  = (u16*)  (ws + 7695360);      // 256*512*2    =   262,144
    u16*   wiT_lo  = (u16*)  (ws + 7957504);
    u16*   w1T_hi  = (u16*)  (ws + 8219648);
    u16*   w1T_lo  = (u16*)  (ws + 8481792);
    u16*   h_hi    = (u16*)  (ws + 8743936);      // 19968*256*2  = 10,223,616
    u16*   h_lo    = (u16*)  (ws + 18967552);
    u16*   xs_hi   = (u16*)  (ws + 29191168);     // 19968*512*2  = 20,447,232
    u16*   xs_lo   = (u16*)  (ws + 49638400);     // end 70,085,632

    k0_prep<<<512 + MTOT / 4, 256, 0, stream>>>(x, gamma, beta, w_in, w1,
                                                wiT_hi, wiT_lo, w1T_hi, w1T_lo,
                                                xs_hi, xs_lo);
    k1_gemm1<<<(MTOT / 128) * 4, 256, 0, stream>>>(xs_hi, xs_lo, wiT_hi, wiT_lo,
                                                   h_hi, h_lo);
    k1g_gbias<<<NFRAME, 256, 0, stream>>>(h_hi, h_lo, w1T_hi, w1T_lo, gbias);
    k1_gemm2<<<(MTOT / 128) * 4, 256, 0, stream>>>(h_hi, h_lo, w1T_hi, w1T_lo,
                                                   w2, gbias, s_quar);
    k2_select<<<NFRAME * 4, 1024, 0, stream>>>(s_quar, noise, hist2);
    k3_output<<<NFRAME * 8, 256, 0, stream>>>(x, hist2, out);
}